// Round 6
// baseline (194.910 us; speedup 1.0000x reference)
//
#include <hip/hip_runtime.h>
#include <hip/hip_bf16.h>

#define NROWS 16384
#define DIN   4096
#define DOUT  4096
#define RNK   64
#define EPSF  1e-7f

typedef float  f32x4  __attribute__((ext_vector_type(4)));
typedef __bf16 bf16x4 __attribute__((ext_vector_type(4)));
typedef __bf16 bf16x8 __attribute__((ext_vector_type(8)));

__device__ __forceinline__ bf16x8 cvt8(f32x4 a, f32x4 b) {
    bf16x8 r;
    r[0]=(__bf16)a.x; r[1]=(__bf16)a.y; r[2]=(__bf16)a.z; r[3]=(__bf16)a.w;
    r[4]=(__bf16)b.x; r[5]=(__bf16)b.y; r[6]=(__bf16)b.z; r[7]=(__bf16)b.w;
    return r;
}

// ---------------------------------------------------------------------------
// KB: per-256-row B slice: bf16-convert, emit Bpf in MFMA-fragment order,
//     and Gram partials. Bpf chunk C=(j*2+ks)*64+l holds
//     B[j*16+(l&15)][ks*32+(l>>4)*8 + 0..7]  (j = 16-col out tile).
// ---------------------------------------------------------------------------
__global__ __launch_bounds__(512, 4)
void kb_gram(const float* __restrict__ Bw, __bf16* __restrict__ Bpf,
             float* __restrict__ Gpart) {
    __shared__ __bf16 bs[256][72];
    const int t = threadIdx.x;
    const int jb = blockIdx.x * 256;

    {   // stage + convert: thread t -> row t>>1, cols (t&1)*32..+31
        const int j0 = t >> 1, c0 = (t & 1) * 32;
        #pragma unroll
        for (int u = 0; u < 4; ++u) {
            f32x4 v0 = *(const f32x4*)&Bw[(size_t)(jb + j0) * RNK + c0 + 8*u];
            f32x4 v1 = *(const f32x4*)&Bw[(size_t)(jb + j0) * RNK + c0 + 8*u + 4];
            *(bf16x8*)&bs[j0][c0 + 8*u] = cvt8(v0, v1);
        }
    }
    __syncthreads();

    // fragment-order write-back: 16 jl x 2 ks x 64 l = 2048 chunks / block
    #pragma unroll
    for (int u = 0; u < 4; ++u) {
        const int lc = t + 512 * u;
        const int ll = lc & 63;
        const int ks = (lc >> 6) & 1;
        const int jl = lc >> 7;
        bf16x8 v = *(const bf16x8*)&bs[jl * 16 + (ll & 15)][ks * 32 + (ll >> 4) * 8];
        const size_t C = ((size_t)((jb >> 4) + jl) * 2 + ks) * 64 + ll;
        *(bf16x8*)&Bpf[C * 8] = v;
    }

    // Gram partial: thread t owns (r = t&63, r' = (t>>6)*8..+7)
    const int r = t & 63, rp = (t >> 6) * 8;
    float acc[8] = {0,0,0,0,0,0,0,0};
    for (int j = 0; j < 256; ++j) {
        float s = (float)bs[j][r];
        bf16x8 v = *(const bf16x8*)&bs[j][rp];   // wave-uniform: broadcast
        #pragma unroll
        for (int u = 0; u < 8; ++u) acc[u] += s * (float)v[u];
    }
    #pragma unroll
    for (int u = 0; u < 8; ++u)
        Gpart[(size_t)blockIdx.x * 4096 + r * 64 + rp + u] = acc[u];
}

__global__ void kc0_sum(const float* __restrict__ Gpart, float* __restrict__ G) {
    const int t = threadIdx.x;   // 256 thr, 16 f32 each
    #pragma unroll
    for (int v = 0; v < 4; ++v) {
        f32x4 a = {0.f, 0.f, 0.f, 0.f};
        for (int b = 0; b < 16; ++b)
            a += *(const f32x4*)&Gpart[(size_t)b * 4096 + t * 16 + v * 4];
        *(f32x4*)&G[t * 16 + v * 4] = a;
    }
}

// ---------------------------------------------------------------------------
// Fused kernel. K-loop changes vs r5:
//  * raw s_barrier (no vmcnt drain!) + explicit lgkmcnt(0) + sched_barrier(0)
//  * 3-deep named register prefetch (tiles k+1,k+2 in flight across barriers)
//  * LDS double-buffer -> 1 barrier per K-iter (WAR safe by barrier collectivity)
// Epilogue (overlaid LDS) unchanged; guarded by a full __syncthreads().
// ---------------------------------------------------------------------------
#define LPK 136
#define BUFSZ 26112   // xs 32*136*2 (8704) + as 64*136*2 (17408)
__global__ __launch_bounds__(512, 4)
void kfused(const float* __restrict__ x, const float* __restrict__ Aw,
            const float* __restrict__ G, const __bf16* __restrict__ Bpf,
            float* __restrict__ out) {
    // region1 (GEMM1): 2 x 26112 = 52224 B (double-buffered xs+as)
    // region2 (epi):   Gs 16384 + s1f 8192 + s1pf 4096 + rowss 128 + gs 128 = 28928 B
    __shared__ __align__(16) char smem[2 * BUFSZ];
    float  (*Gs)[64]       = (float (*)[64])(smem);
    float  (*s1f)[64]      = (float (*)[64])(smem + 16384);
    __bf16 (*s1pf)[2][64][8] = (__bf16 (*)[2][64][8])(smem + 24576);
    float  *rowss          = (float*)(smem + 28672);
    float  *gsc            = (float*)(smem + 28800);

    const int t = threadIdx.x;
    const int l = t & 63;
    const int w = t >> 6;
    const int brow = blockIdx.x * 32;

    // ---- GEMM1 ----
    const int xrow = t >> 4, xcol = (t & 15) * 8;   // x: 32x128
    const int arow = t >> 3, acol = (t & 7) * 16;   // A: 64x128
    const size_t xb = (size_t)(brow + xrow) * DIN + xcol;
    const size_t ab = (size_t)arow * DIN + acol;

    const int m0   = (w & 1) * 16;
    const int n0   = (w >> 1) * 16;
    const int frow = l & 15;
    const int koff = (l >> 4) * 8;

    float ssq = 0.f;
    f32x4 acc = {0.f, 0.f, 0.f, 0.f};
    // 3 named prefetch sets (A/B/C), 6 f32x4 each
    f32x4 xA0,xA1,aA0,aA1,aA2,aA3;
    f32x4 xB0,xB1,aB0,aB1,aB2,aB3;
    f32x4 xC0,xC1,aC0,aC1,aC2,aC3;

    auto load = [&](f32x4&x0,f32x4&x1,f32x4&A0,f32x4&A1,f32x4&A2,f32x4&A3,int kt){
        const size_t o = (size_t)kt * 128;
        x0 = *(const f32x4*)&x[xb + o];       x1 = *(const f32x4*)&x[xb + o + 4];
        A0 = *(const f32x4*)&Aw[ab + o];      A1 = *(const f32x4*)&Aw[ab + o + 4];
        A2 = *(const f32x4*)&Aw[ab + o + 8];  A3 = *(const f32x4*)&Aw[ab + o + 12];
    };
    auto consume = [&](const f32x4&x0,const f32x4&x1,const f32x4&A0,
                       const f32x4&A1,const f32x4&A2,const f32x4&A3, int par){
        __bf16 (*xsp)[LPK] = (__bf16 (*)[LPK])(smem + par * BUFSZ);
        __bf16 (*asp)[LPK] = (__bf16 (*)[LPK])(smem + par * BUFSZ + 8704);
        ssq += x0.x*x0.x + x0.y*x0.y + x0.z*x0.z + x0.w*x0.w;
        ssq += x1.x*x1.x + x1.y*x1.y + x1.z*x1.z + x1.w*x1.w;
        *(bf16x8*)&xsp[xrow][xcol]     = cvt8(x0, x1);
        *(bf16x8*)&asp[arow][acol]     = cvt8(A0, A1);
        *(bf16x8*)&asp[arow][acol + 8] = cvt8(A2, A3);
        // raw barrier: drain LDS only (NOT vmcnt -> prefetch stays in flight)
        __builtin_amdgcn_sched_barrier(0);
        asm volatile("s_waitcnt lgkmcnt(0)" ::: "memory");
        __builtin_amdgcn_s_barrier();
        __builtin_amdgcn_sched_barrier(0);
        #pragma unroll
        for (int ks = 0; ks < 4; ++ks) {
            bf16x8 af  = *(const bf16x8*)&xsp[m0 + frow][ks*32 + koff];
            bf16x8 bf_ = *(const bf16x8*)&asp[n0 + frow][ks*32 + koff];
            acc = __builtin_amdgcn_mfma_f32_16x16x32_bf16(af, bf_, acc, 0, 0, 0);
        }
        // no trailing barrier: WAR on buf par is protected by the barrier of
        // iteration k+1 (collective) before anyone writes buf par again (k+2).
    };

    // NT = 32 tiles of BK=128. 3-deep pipeline, unrolled by 3 (static indices).
    load(xA0,xA1,aA0,aA1,aA2,aA3, 0);
    load(xB0,xB1,aB0,aB1,aB2,aB3, 1);
    for (int kt = 0; kt < 30; kt += 3) {
        load(xC0,xC1,aC0,aC1,aC2,aC3, kt + 2);
        consume(xA0,xA1,aA0,aA1,aA2,aA3, kt & 1);
        load(xA0,xA1,aA0,aA1,aA2,aA3, kt + 3);
        consume(xB0,xB1,aB0,aB1,aB2,aB3, (kt + 1) & 1);
        load(xB0,xB1,aB0,aB1,aB2,aB3, kt + 4);
        consume(xC0,xC1,aC0,aC1,aC2,aC3, kt & 1);
    }
    consume(xA0,xA1,aA0,aA1,aA2,aA3, 0);   // tile 30
    consume(xB0,xB1,aB0,aB1,aB2,aB3, 1);   // tile 31
    __syncthreads();   // all waves' LDS reads done; region1 dead, region2 live

    // ---- stage G (L2-hit, 16 KB) + sinh scale partials ----
    {
        float* gf = &Gs[0][0];
        *(f32x4*)&gf[t * 8]     = *(const f32x4*)&G[t * 8];
        *(f32x4*)&gf[t * 8 + 4] = *(const f32x4*)&G[t * 8 + 4];
    }
    ssq += __shfl_xor(ssq, 1);
    ssq += __shfl_xor(ssq, 2);
    ssq += __shfl_xor(ssq, 4);
    ssq += __shfl_xor(ssq, 8);
    if ((l & 15) == 0) rowss[w * 4 + (l >> 4)] = ssq;
    __syncthreads();
    if (t < 32) {
        float vn = fmaxf(sqrtf(rowss[t]), EPSF);
        rowss[t] = sinhf(vn) / vn;
    }
    __syncthreads();

    // ---- scaled s1 (f32) to LDS ----
    #pragma unroll
    for (int q = 0; q < 4; ++q) {
        const int row = m0 + (l >> 4) * 4 + q;
        s1f[row][n0 + frow] = rowss[row] * acc[q];
    }
    __syncthreads();

    // ---- r2 = s1^T G s1 per row; wave w owns rows 4w..4w+3 ----
    {
        const int r0 = w * 4;
        float y0=0.f, y1=0.f, y2=0.f, y3=0.f;
        for (int r = 0; r < 64; ++r) {
            const float gr = Gs[r][l];          // lanes consecutive: conflict-free
            y0 += gr * s1f[r0 + 0][r];          // wave-uniform: broadcast
            y1 += gr * s1f[r0 + 1][r];
            y2 += gr * s1f[r0 + 2][r];
            y3 += gr * s1f[r0 + 3][r];
        }
        float q0 = s1f[r0 + 0][l] * y0;
        float q1 = s1f[r0 + 1][l] * y1;
        float q2 = s1f[r0 + 2][l] * y2;
        float q3 = s1f[r0 + 3][l] * y3;
        #pragma unroll
        for (int s = 1; s < 64; s <<= 1) {
            q0 += __shfl_xor(q0, s);
            q1 += __shfl_xor(q1, s);
            q2 += __shfl_xor(q2, s);
            q3 += __shfl_xor(q3, s);
        }
        if (l == 0) {
            float r2v[4] = {q0, q1, q2, q3};
            #pragma unroll
            for (int i = 0; i < 4; ++i) {
                const float r2 = r2v[i];
                const float rn = sqrtf(r2);
                gsc[r0 + i] = 0.25f * acoshf(fmaxf(sqrtf(1.f + r2), 1.f + EPSF))
                                    / fmaxf(rn, EPSF);
            }
        }
    }
    __syncthreads();

    // ---- build s1pf (bf16, fragment order, g folded in) ----
    if (t < 256) {
        const int ll = t & 63, ksq = (t >> 6) & 1, mg = t >> 7;
        const int row = mg * 16 + (ll & 15);
        const int kc  = ksq * 32 + (ll >> 4) * 8;
        const float gg = gsc[row];
        bf16x8 p;
        #pragma unroll
        for (int u = 0; u < 8; ++u) p[u] = (__bf16)(gg * s1f[row][kc + u]);
        *(bf16x8*)&s1pf[mg][ksq][ll][0] = p;
    }
    __syncthreads();

    // ---- GEMM2: barrier-free, B fragments straight from L2 ----
    {
        const int mg = w & 1;
        const int mr0 = mg * 16;
        const bf16x8 a0f = *(const bf16x8*)&s1pf[mg][0][l][0];
        const bf16x8 a1f = *(const bf16x8*)&s1pf[mg][1][l][0];
        #pragma unroll 4
        for (int jj = 0; jj < 64; ++jj) {
            const int j = (w >> 1) + jj * 4;
            const size_t base = ((size_t)j * 2 * 64 + l) * 8;
            bf16x8 b0 = *(const bf16x8*)&Bpf[base];
            bf16x8 b1 = *(const bf16x8*)&Bpf[base + 512];
            f32x4 a2 = {0.f, 0.f, 0.f, 0.f};
            a2 = __builtin_amdgcn_mfma_f32_16x16x32_bf16(a0f, b0, a2, 0, 0, 0);
            a2 = __builtin_amdgcn_mfma_f32_16x16x32_bf16(a1f, b1, a2, 0, 0, 0);
            const int col = j * 16 + frow;
            #pragma unroll
            for (int q = 0; q < 4; ++q) {
                const int row = mr0 + (l >> 4) * 4 + q;
                out[(size_t)(brow + row) * DOUT + col] = a2[q];
            }
        }
    }
}

extern "C" void kernel_launch(void* const* d_in, const int* in_sizes, int n_in,
                              void* d_out, int out_size, void* d_ws, size_t ws_size,
                              hipStream_t stream) {
    const float* x  = (const float*)d_in[0];   // (16384, 4096)
    const float* Aw = (const float*)d_in[1];   // (64, 4096)
    const float* Bw = (const float*)d_in[2];   // (4096, 64)
    float* out = (float*)d_out;

    char* ws = (char*)d_ws;
    __bf16* Bpf   = (__bf16*)(ws);              // 512 KB (fragment order)
    float*  Gpart = (float*)(ws + 524288);      // 256 KB
    float*  G     = (float*)(ws + 786432);      // 16 KB

    kb_gram<<<16, 512, 0, stream>>>(Bw, Bpf, Gpart);
    kc0_sum<<<1, 256, 0, stream>>>(Gpart, G);
    kfused<<<NROWS / 32, 512, 0, stream>>>(x, Aw, G, Bpf, out);
}

// Round 7
// 178.616 us; speedup vs baseline: 1.0912x; 1.0912x over previous
//
#include <hip/hip_runtime.h>
#include <hip/hip_bf16.h>

#define NROWS 16384
#define DIN   4096
#define DOUT  4096
#define RNK   64
#define EPSF  1e-7f

typedef float  f32x4  __attribute__((ext_vector_type(4)));
typedef __bf16 bf16x4 __attribute__((ext_vector_type(4)));
typedef __bf16 bf16x8 __attribute__((ext_vector_type(8)));

__device__ __forceinline__ bf16x8 cvt8(f32x4 a, f32x4 b) {
    bf16x8 r;
    r[0]=(__bf16)a.x; r[1]=(__bf16)a.y; r[2]=(__bf16)a.z; r[3]=(__bf16)a.w;
    r[4]=(__bf16)b.x; r[5]=(__bf16)b.y; r[6]=(__bf16)b.z; r[7]=(__bf16)b.w;
    return r;
}
__device__ __forceinline__ bf16x4 cvt4(f32x4 v) {
    bf16x4 r;
    r[0]=(__bf16)v.x; r[1]=(__bf16)v.y; r[2]=(__bf16)v.z; r[3]=(__bf16)v.w;
    return r;
}

// ---------------------------------------------------------------------------
// KA: Apf = Aw in bf16 MFMA-fragment order.
// Chunk (kt, ng, l): Apf[(kt*4+ng)*512 + l*8 + j] = Aw[ng*16+(l&15)][kt*32+(l>>4)*8+j]
// ---------------------------------------------------------------------------
__global__ __launch_bounds__(512, 2)
void ka_apf(const float* __restrict__ Aw, __bf16* __restrict__ Apf) {
    const int kt = blockIdx.x;           // 128 k-steps
    const int t = threadIdx.x;
    const int ng = t >> 7, le = (t >> 1) & 63, h = t & 1;
    f32x4 v = *(const f32x4*)&Aw[(size_t)(ng*16 + (le&15)) * DIN + kt*32 + (le>>4)*8 + h*4];
    *(bf16x4*)&Apf[((size_t)(kt*4 + ng))*512 + le*8 + h*4] = cvt4(v);
}

// ---------------------------------------------------------------------------
// KB: per-256-row B slice: bf16-convert, emit Bpf in MFMA-fragment order,
//     and Gram partials (G = B^T B, symmetric).
// ---------------------------------------------------------------------------
__global__ __launch_bounds__(512, 4)
void kb_gram(const float* __restrict__ Bw, __bf16* __restrict__ Bpf,
             float* __restrict__ Gpart) {
    __shared__ __bf16 bs[256][72];
    const int t = threadIdx.x;
    const int jb = blockIdx.x * 256;

    {   // stage + convert: thread t -> row t>>1, cols (t&1)*32..+31
        const int j0 = t >> 1, c0 = (t & 1) * 32;
        #pragma unroll
        for (int u = 0; u < 4; ++u) {
            f32x4 v0 = *(const f32x4*)&Bw[(size_t)(jb + j0) * RNK + c0 + 8*u];
            f32x4 v1 = *(const f32x4*)&Bw[(size_t)(jb + j0) * RNK + c0 + 8*u + 4];
            *(bf16x8*)&bs[j0][c0 + 8*u] = cvt8(v0, v1);
        }
    }
    __syncthreads();

    // fragment-order write-back
    #pragma unroll
    for (int u = 0; u < 4; ++u) {
        const int lc = t + 512 * u;
        const int ll = lc & 63;
        const int ks = (lc >> 6) & 1;
        const int jl = lc >> 7;
        bf16x8 v = *(const bf16x8*)&bs[jl * 16 + (ll & 15)][ks * 32 + (ll >> 4) * 8];
        const size_t C = ((size_t)((jb >> 4) + jl) * 2 + ks) * 64 + ll;
        *(bf16x8*)&Bpf[C * 8] = v;
    }

    // Gram partial
    const int r = t & 63, rp = (t >> 6) * 8;
    float acc[8] = {0,0,0,0,0,0,0,0};
    for (int j = 0; j < 256; ++j) {
        float s = (float)bs[j][r];
        bf16x8 v = *(const bf16x8*)&bs[j][rp];
        #pragma unroll
        for (int u = 0; u < 8; ++u) acc[u] += s * (float)v[u];
    }
    #pragma unroll
    for (int u = 0; u < 8; ++u)
        Gpart[(size_t)blockIdx.x * 4096 + r * 64 + rp + u] = acc[u];
}

__global__ void kc0_sum(const float* __restrict__ Gpart, float* __restrict__ G) {
    const int t = threadIdx.x;
    #pragma unroll
    for (int v = 0; v < 4; ++v) {
        f32x4 a = {0.f, 0.f, 0.f, 0.f};
        for (int b = 0; b < 16; ++b)
            a += *(const f32x4*)&Gpart[(size_t)b * 4096 + t * 16 + v * 4];
        *(f32x4*)&G[t * 16 + v * 4] = a;
    }
}

// ---------------------------------------------------------------------------
// K1: 16 rows per block, 4 waves splitting K 4-ways. Streaming, barrier-free
// K-loop: x direct from HBM (lane = 32B of its row), Apf fragments from L2.
// mfma(Apf_frag, x_frag) -> lane holds 4 consecutive r of one row.
// Epilogue: cross-wave reduce -> sinh scale -> r2 = s1^T G s1 -> g ->
// s1pf bf16 fragment-order. 3 barriers per block total.
// ---------------------------------------------------------------------------
__global__ __launch_bounds__(256, 4)
void k1(const float* __restrict__ x, const __bf16* __restrict__ Apf,
        const float* __restrict__ G, __bf16* __restrict__ s1pf) {
    __shared__ float part[4][16][68];    // 17408 B (+4 pad: kills bank conflicts)
    __shared__ float Gs[64][64];         // 16384 B
    __shared__ float s1s[16][68];        // 4352 B
    __shared__ float ssqs[4][16];
    __shared__ float gsl[16];

    const int t = threadIdx.x, l = t & 63, w = t >> 6;
    const int brow = blockIdx.x * 16;
    const int rl = l & 15, ko = l >> 4;

    const size_t xoff = (size_t)(brow + rl) * DIN + (size_t)w * 1024 + ko * 8;
    const size_t aoff = (size_t)(w * 32) * 2048 + (size_t)l * 8;

    f32x4 acc0 = {0,0,0,0}, acc1 = {0,0,0,0}, acc2 = {0,0,0,0}, acc3 = {0,0,0,0};
    float ssq = 0.f;

    // depth-1 register prefetch, fully unrolled (static indices)
    f32x4 xc0 = *(const f32x4*)&x[xoff];
    f32x4 xc1 = *(const f32x4*)&x[xoff + 4];
    bf16x8 a0 = *(const bf16x8*)&Apf[aoff];
    bf16x8 a1 = *(const bf16x8*)&Apf[aoff + 512];
    bf16x8 a2 = *(const bf16x8*)&Apf[aoff + 1024];
    bf16x8 a3 = *(const bf16x8*)&Apf[aoff + 1536];

    #pragma unroll
    for (int i = 0; i < 32; ++i) {
        f32x4 xn0 = xc0, xn1 = xc1;
        bf16x8 b0 = a0, b1 = a1, b2 = a2, b3 = a3;
        if (i < 31) {
            xn0 = *(const f32x4*)&x[xoff + (i+1)*32];
            xn1 = *(const f32x4*)&x[xoff + (i+1)*32 + 4];
            const size_t ao = aoff + (size_t)(i+1)*2048;
            b0 = *(const bf16x8*)&Apf[ao];
            b1 = *(const bf16x8*)&Apf[ao + 512];
            b2 = *(const bf16x8*)&Apf[ao + 1024];
            b3 = *(const bf16x8*)&Apf[ao + 1536];
        }
        ssq += xc0.x*xc0.x + xc0.y*xc0.y + xc0.z*xc0.z + xc0.w*xc0.w;
        ssq += xc1.x*xc1.x + xc1.y*xc1.y + xc1.z*xc1.z + xc1.w*xc1.w;
        bf16x8 xf = cvt8(xc0, xc1);
        acc0 = __builtin_amdgcn_mfma_f32_16x16x32_bf16(a0, xf, acc0, 0, 0, 0);
        acc1 = __builtin_amdgcn_mfma_f32_16x16x32_bf16(a1, xf, acc1, 0, 0, 0);
        acc2 = __builtin_amdgcn_mfma_f32_16x16x32_bf16(a2, xf, acc2, 0, 0, 0);
        acc3 = __builtin_amdgcn_mfma_f32_16x16x32_bf16(a3, xf, acc3, 0, 0, 0);
        xc0 = xn0; xc1 = xn1; a0 = b0; a1 = b1; a2 = b2; a3 = b3;
    }

    // dump wave partials: acc[ng][q] = s1part[row=rl][ng*16 + ko*4 + q]
    *(f32x4*)&part[w][rl][ 0 + ko*4] = acc0;
    *(f32x4*)&part[w][rl][16 + ko*4] = acc1;
    *(f32x4*)&part[w][rl][32 + ko*4] = acc2;
    *(f32x4*)&part[w][rl][48 + ko*4] = acc3;
    // ssq: lane holds row rl partial over this wave's k-range; sum ko copies
    ssq += __shfl_xor(ssq, 16);
    ssq += __shfl_xor(ssq, 32);
    if (l < 16) ssqs[w][l] = ssq;
    // stage G (L2 hit): 4096 f32 / 256 thr = 16 each
    {
        float* gf = &Gs[0][0];
        const float* gp = &G[t * 16];
        *(f32x4*)&gf[t*16 + 0]  = *(const f32x4*)&gp[0];
        *(f32x4*)&gf[t*16 + 4]  = *(const f32x4*)&gp[4];
        *(f32x4*)&gf[t*16 + 8]  = *(const f32x4*)&gp[8];
        *(f32x4*)&gf[t*16 + 12] = *(const f32x4*)&gp[12];
    }
    __syncthreads();

    // reduce 4 wave-partials + sinh scale. thread t: row t>>4, cols (t&15)*4..+3
    const int row = t >> 4, c4 = (t & 15) * 4;
    f32x4 s = *(const f32x4*)&part[0][row][c4];
    s += *(const f32x4*)&part[1][row][c4];
    s += *(const f32x4*)&part[2][row][c4];
    s += *(const f32x4*)&part[3][row][c4];
    const float ssqt = ssqs[0][row] + ssqs[1][row] + ssqs[2][row] + ssqs[3][row];
    const float vn = fmaxf(sqrtf(ssqt), EPSF);
    const float sc = sinhf(vn) / vn;
    s *= sc;
    *(f32x4*)&s1s[row][c4] = s;
    __syncthreads();

    // r2 = s1^T G s1 (G symmetric: Gs[j][i] == G[i][j])
    f32x4 yacc = {0,0,0,0};
    for (int j = 0; j < 64; ++j) {
        const float sj = s1s[row][j];
        yacc += *(const f32x4*)&Gs[j][c4] * sj;
    }
    float r2p = s.x*yacc.x + s.y*yacc.y + s.z*yacc.z + s.w*yacc.w;
    r2p += __shfl_xor(r2p, 1);
    r2p += __shfl_xor(r2p, 2);
    r2p += __shfl_xor(r2p, 4);
    r2p += __shfl_xor(r2p, 8);
    if ((t & 15) == 0) {
        const float r2 = r2p;
        const float rn = sqrtf(r2);
        gsl[row] = 0.25f * acoshf(fmaxf(sqrtf(1.f + r2), 1.f + EPSF))
                         / fmaxf(rn, EPSF);   // ALPHA/RANK = 0.25
    }
    __syncthreads();

    // emit s1pf fragments: chunk (blockIdx*2 + ks)*64 + le
    if (t < 128) {
        const int le = t & 63, ks = t >> 6;
        const int er = le & 15, ec = ks * 32 + (le >> 4) * 8;
        const float g = gsl[er];
        bf16x8 p;
        #pragma unroll
        for (int u = 0; u < 8; ++u) p[u] = (__bf16)(g * s1s[er][ec + u]);
        *(bf16x8*)&s1pf[((size_t)(blockIdx.x * 2 + ks) * 64 + le) * 8] = p;
    }
}

// ---------------------------------------------------------------------------
// K2: out = s1p @ Bw^T. Zero LDS, zero barriers. 64x64 tile per block,
// 4 waves = 4 row-groups. mfma(Bpf_frag, s1pf_frag) -> lane holds 4
// consecutive out-cols of one row -> dwordx4 stores (full 64B sectors).
// ---------------------------------------------------------------------------
__global__ __launch_bounds__(256, 4)
void k2(const __bf16* __restrict__ s1pf, const __bf16* __restrict__ Bpf,
        float* __restrict__ out) {
    const int t = threadIdx.x, l = t & 63, w = t >> 6;
    const int rt = blockIdx.x >> 6;      // 256 row tiles
    const int ct = blockIdx.x & 63;      // 64 col tiles
    const int g16 = rt * 4 + w;          // this wave's 16-row group

    const bf16x8 sf0 = *(const bf16x8*)&s1pf[((size_t)(g16*2 + 0) * 64 + l) * 8];
    const bf16x8 sf1 = *(const bf16x8*)&s1pf[((size_t)(g16*2 + 1) * 64 + l) * 8];

    f32x4 acc[4];
    #pragma unroll
    for (int ng = 0; ng < 4; ++ng) {
        const size_t base = ((size_t)((ct*4 + ng)*2) * 64 + l) * 8;
        bf16x8 b0 = *(const bf16x8*)&Bpf[base];
        bf16x8 b1 = *(const bf16x8*)&Bpf[base + 512];
        f32x4 a = {0.f, 0.f, 0.f, 0.f};
        a = __builtin_amdgcn_mfma_f32_16x16x32_bf16(b0, sf0, a, 0, 0, 0);
        a = __builtin_amdgcn_mfma_f32_16x16x32_bf16(b1, sf1, a, 0, 0, 0);
        acc[ng] = a;
    }

    const int orow = rt * 64 + w * 16 + (l & 15);
    const size_t ob = (size_t)orow * DOUT + ct * 64 + (l >> 4) * 4;
    #pragma unroll
    for (int ng = 0; ng < 4; ++ng)
        *(f32x4*)&out[ob + ng * 16] = acc[ng];
}

extern "C" void kernel_launch(void* const* d_in, const int* in_sizes, int n_in,
                              void* d_out, int out_size, void* d_ws, size_t ws_size,
                              hipStream_t stream) {
    const float* x  = (const float*)d_in[0];   // (16384, 4096)
    const float* Aw = (const float*)d_in[1];   // (64, 4096)
    const float* Bw = (const float*)d_in[2];   // (4096, 64)
    float* out = (float*)d_out;

    char* ws = (char*)d_ws;
    __bf16* Apf   = (__bf16*)(ws);                  // 512 KB
    __bf16* Bpf   = (__bf16*)(ws + 0x080000);       // 512 KB
    float*  Gpart = (float*)(ws + 0x100000);        // 256 KB
    float*  G     = (float*)(ws + 0x140000);        // 16 KB
    __bf16* s1pf  = (__bf16*)(ws + 0x150000);       // 2 MB

    ka_apf<<<128, 512, 0, stream>>>(Aw, Apf);
    kb_gram<<<16, 512, 0, stream>>>(Bw, Bpf, Gpart);
    kc0_sum<<<1, 256, 0, stream>>>(Gpart, G);
    k1<<<NROWS / 16, 256, 0, stream>>>(x, Apf, G, s1pf);
    k2<<<16384, 256, 0, stream>>>(s1pf, Bpf, out);
}